// Round 1
// baseline (2044.540 us; speedup 1.0000x reference)
//
#include <hip/hip_runtime.h>
#include <stdint.h>

typedef uint32_t u32;
typedef uint64_t u64;

#define KREN 1000
#define WIMG 256
#define HIMG 256
#define CAND_CAP 2048
#define GSTRIDE 12

// ---------- monotonic float -> u32 key (larger key == larger float) ----------
__device__ __forceinline__ u32 fkey(float f) {
  u32 b = __float_as_uint(f);
  return (b & 0x80000000u) ? ~b : (b | 0x80000000u);
}

// ---------- init: zero hist + state, set K ----------
__global__ void k_init(u32* __restrict__ hist, u32* __restrict__ state) {
  int t = threadIdx.x;
  hist[t] = 0;
  if (t < 8) state[t] = (t == 1) ? (u32)KREN : 0u;
}

// ---------- compute depth keys + level-0 (bits 31:24) histogram ----------
__global__ void k_keys(const float* __restrict__ pos, const float* __restrict__ cam,
                       u32* __restrict__ keys, u32* __restrict__ hist, int N) {
  __shared__ u32 h[256];
  for (int i = threadIdx.x; i < 256; i += blockDim.x) h[i] = 0;
  __syncthreads();
  float c8 = cam[8], c9 = cam[9], c10 = cam[10], c11 = cam[11];
  int stride = gridDim.x * blockDim.x;
  for (int i = blockIdx.x * blockDim.x + threadIdx.x; i < N; i += stride) {
    float x = pos[3 * i], y = pos[3 * i + 1], z = pos[3 * i + 2];
    float d = c8 * x + c9 * y + c10 * z + c11;
    u32 mk = fkey(d);
    keys[i] = mk;
    atomicAdd(&h[mk >> 24], 1u);
  }
  __syncthreads();
  for (int i = threadIdx.x; i < 256; i += blockDim.x)
    if (h[i]) atomicAdd(&hist[i], h[i]);
}

// ---------- histogram of byte (shift..shift+7) among items matching prefix ----------
__global__ void k_hist(const u32* __restrict__ keys, u32* __restrict__ hist,
                       const u32* __restrict__ state, int shift, int N) {
  u32 pref = state[0];
  u32 mask = ~((1u << (shift + 8)) - 1u);
  int stride = gridDim.x * blockDim.x;
  for (int i = blockIdx.x * blockDim.x + threadIdx.x; i < N; i += stride) {
    u32 k = keys[i];
    if ((k & mask) == pref) atomicAdd(&hist[(k >> shift) & 255u], 1u);
  }
}

// ---------- pick the bin holding the K-th largest; update prefix; clear hist ----------
__global__ void k_pick(u32* __restrict__ hist, u32* __restrict__ state, int shift) {
  __shared__ u32 h[256];
  int t = threadIdx.x;
  h[t] = hist[t];
  hist[t] = 0;  // ready for next level
  __syncthreads();
  if (t == 0) {
    u32 K = state[1];
    u32 cum = 0;
    int b = 255;
    for (; b >= 0; --b) {
      cum += h[b];
      if (cum >= K) break;
    }
    if (b < 0) b = 0;  // defensive; invariant guarantees break
    u32 above = cum - h[b];          // count strictly greater bins
    state[1] = K - above;            // remaining needed inside bin b
    state[0] |= ((u32)b) << shift;   // extend prefix
  }
}

// ---------- collect all candidates with key >= threshold ----------
__global__ void k_collect(const u32* __restrict__ keys, u32* __restrict__ state,
                          u64* __restrict__ cand, int N) {
  u32 T = state[0];
  int stride = gridDim.x * blockDim.x;
  for (int i = blockIdx.x * blockDim.x + threadIdx.x; i < N; i += stride) {
    u32 k = keys[i];
    if (k >= T) {
      u32 p = atomicAdd(&state[2], 1u);
      if (p < CAND_CAP) cand[p] = (((u64)(~k)) << 32) | (u32)i;
    }
  }
}

// ---------- single block: bitonic sort candidates, preprocess top-K gaussians ----------
__global__ __launch_bounds__(1024) void k_sortprep(
    const u32* __restrict__ state, const u64* __restrict__ cand,
    const float* __restrict__ pos, const float* __restrict__ scales,
    const float* __restrict__ rot, const float* __restrict__ colors,
    const float* __restrict__ opacity, const float* __restrict__ csh,
    const float* __restrict__ cam, const float* __restrict__ campos,
    float* __restrict__ gauss, int shstride) {
  __shared__ u64 s[CAND_CAP];
  int tid = threadIdx.x;
  int M = (int)state[2];
  if (M > CAND_CAP) M = CAND_CAP;
  for (int i = tid; i < CAND_CAP; i += 1024) s[i] = (i < M) ? cand[i] : ~0ull;
  __syncthreads();
  // bitonic ascending: key = (~depthkey, index) => depth desc, index asc (stable)
  for (int k = 2; k <= CAND_CAP; k <<= 1) {
    for (int j = k >> 1; j > 0; j >>= 1) {
      for (int t = tid; t < CAND_CAP; t += 1024) {
        int ixj = t ^ j;
        if (ixj > t) {
          u64 a = s[t], b = s[ixj];
          bool up = ((t & k) == 0);
          if (up ? (a > b) : (a < b)) { s[t] = b; s[ixj] = a; }
        }
      }
      __syncthreads();
    }
  }
  if (tid < KREN) {
    int g = (int)(u32)(s[tid] & 0xffffffffu);
    float x = pos[3 * g], y = pos[3 * g + 1], z = pos[3 * g + 2];
    float c0 = cam[0], c1 = cam[1], c2 = cam[2], c3 = cam[3];
    float c4 = cam[4], c5 = cam[5], c6 = cam[6], c7 = cam[7];
    float c8 = cam[8], c9 = cam[9], c10 = cam[10], c11 = cam[11];
    float dep = c8 * x + c9 * y + c10 * z + c11;
    float invd = 1.0f / (dep + 1e-7f);
    float p2x = (c0 * x + c1 * y + c2 * z + c3) * invd;
    float p2y = (c4 * x + c5 * y + c6 * z + c7) * invd;
    // normalized quaternion -> rotation matrix
    float qw = rot[4 * g], qx = rot[4 * g + 1], qy = rot[4 * g + 2], qz = rot[4 * g + 3];
    float qn = rsqrtf(qw * qw + qx * qx + qy * qy + qz * qz);
    qw *= qn; qx *= qn; qy *= qn; qz *= qn;
    float r00 = 1.f - 2.f * (qy * qy + qz * qz), r01 = 2.f * (qx * qy - qw * qz), r02 = 2.f * (qx * qz + qw * qy);
    float r10 = 2.f * (qx * qy + qw * qz), r11 = 1.f - 2.f * (qx * qx + qz * qz), r12 = 2.f * (qy * qz - qw * qx);
    float r20 = 2.f * (qx * qz - qw * qy), r21 = 2.f * (qy * qz + qw * qx), r22 = 1.f - 2.f * (qx * qx + qy * qy);
    float e0 = fmaxf(expf(scales[3 * g]), 1e-7f);
    float e1 = fmaxf(expf(scales[3 * g + 1]), 1e-7f);
    float e2 = fmaxf(expf(scales[3 * g + 2]), 1e-7f);
    float v0 = e0 * e0, v1 = e1 * e1, v2 = e2 * e2;
    float C00 = r00 * r00 * v0 + r01 * r01 * v1 + r02 * r02 * v2;
    float C01 = r00 * r10 * v0 + r01 * r11 * v1 + r02 * r12 * v2;
    float C02 = r00 * r20 * v0 + r01 * r21 * v1 + r02 * r22 * v2;
    float C11 = r10 * r10 * v0 + r11 * r11 * v1 + r12 * r12 * v2;
    float C12 = r10 * r20 * v0 + r11 * r21 * v1 + r12 * r22 * v2;
    float C22 = r20 * r20 * v0 + r21 * r21 * v1 + r22 * r22 * v2;
    float fx = c0, fy = c5;
    float jd = 1.0f / dep;  // reference J uses raw depth (no epsilon)
    float j0 = fx * jd, j2 = -fx * p2x * jd, j4 = fy * jd, j5 = -fy * p2y * jd;
    float u0x = j0 * C00 + j2 * C02;
    float u0y = j0 * C01 + j2 * C12;
    float u0z = j0 * C02 + j2 * C22;
    float u1y = j4 * C11 + j5 * C12;
    float u1z = j4 * C12 + j5 * C22;
    float a = u0x * j0 + u0z * j2 + 1e-6f;
    float b = u0y * j4 + u0z * j5;          // symmetric: b == cc
    float d2 = u1y * j4 + u1z * j5 + 1e-6f;
    float det = a * d2 - b * b;
    float idet = 1.0f / det;
    const float L = 1.4426950408889634f;    // log2(e)
    float Aq = -0.5f * L * d2 * idet;       // exp(-0.5*qv) == exp2(Aq dx^2 + Bq dxdy + Cq dy^2)
    float Bq = L * b * idet;                // (b+cc)/2 folded with sign
    float Cq = -0.5f * L * a * idet;
    // SH color
    float vx = x - campos[0], vy = y - campos[1], vz = z - campos[2];
    float vn = rsqrtf(vx * vx + vy * vy + vz * vz);
    vx *= vn; vy *= vn; vz *= vn;
    float sh[9];
    sh[0] = 0.28209479177387814f;
    sh[1] = -0.48860251190291987f * vy;
    sh[2] = 0.48860251190291987f * vz;
    sh[3] = -0.48860251190291987f * vx;
    sh[4] = 1.0925484305920792f * vx * vy;
    sh[5] = -1.0925484305920792f * vy * vz;
    sh[6] = 0.31539156525252005f * (2.f * vz * vz - vx * vx - vy * vy);
    sh[7] = -1.0925484305920792f * vx * vz;
    sh[8] = 0.5462742152960396f * (vx * vx - vy * vy);
    float col[3];
    for (int c = 0; c < 3; ++c) {
      float accv = colors[3 * g + c];
      for (int k2 = 0; k2 < 9; ++k2) accv += sh[k2] * csh[(size_t)g * shstride + 3 * k2 + c];
      col[c] = 1.0f / (1.0f + __expf(-accv));
    }
    float op = 1.0f / (1.0f + __expf(-opacity[g]));
    float* G = gauss + tid * GSTRIDE;
    G[0] = p2x; G[1] = p2y; G[2] = Aq; G[3] = Bq; G[4] = Cq;
    G[5] = op;  G[6] = col[0]; G[7] = col[1]; G[8] = col[2];
    G[9] = 0.f; G[10] = 0.f; G[11] = 0.f;
  }
}

// ---------- render: one thread per pixel, gaussians staged in LDS ----------
__global__ __launch_bounds__(256) void k_render(const float* __restrict__ gauss,
                                                float* __restrict__ out) {
  __shared__ float gs[KREN * GSTRIDE];  // 48 KB
  for (int i = threadIdx.x; i < KREN * GSTRIDE; i += 256) gs[i] = gauss[i];
  __syncthreads();
  int p = blockIdx.x * 256 + threadIdx.x;
  float px = (float)(p & (WIMG - 1));
  float py = (float)(p >> 8);
  float cr = 0.f, cg = 0.f, cb = 0.f, acc = 0.f;
  for (int k = 0; k < KREN; ++k) {
    const float4* G = (const float4*)(gs + k * GSTRIDE);
    float4 g0 = G[0];
    float4 g1 = G[1];
    float g2x = gs[k * GSTRIDE + 8];
    float dx = px - g0.x, dy = py - g0.y;
    float sE = g0.z * dx * dx + g0.w * dx * dy + g1.x * dy * dy;
    float alpha = g1.y * exp2f(sE);
    float w = (1.0f - acc) * alpha;
    cr += w * g1.z; cg += w * g1.w; cb += w * g2x;
    acc += w;
  }
  out[3 * p + 0] = cr;
  out[3 * p + 1] = cg;
  out[3 * p + 2] = cb;
}

extern "C" void kernel_launch(void* const* d_in, const int* in_sizes, int n_in,
                              void* d_out, int out_size, void* d_ws, size_t ws_size,
                              hipStream_t stream) {
  const float* positions = (const float*)d_in[0];
  const float* scales    = (const float*)d_in[1];
  const float* rotations = (const float*)d_in[2];
  const float* colors    = (const float*)d_in[3];
  const float* opacity   = (const float*)d_in[4];
  const float* colors_sh = (const float*)d_in[5];
  const float* cam       = (const float*)d_in[6];
  const float* campos    = (const float*)d_in[7];
  int N = in_sizes[0] / 3;
  int shstride = in_sizes[5] / N;  // = SH_COEFFS * 3 = 48

  char* ws = (char*)d_ws;
  size_t keyBytes = (((size_t)N * 4) + 255) & ~(size_t)255;
  u32* keys  = (u32*)ws;
  u32* hist  = (u32*)(ws + keyBytes);
  u32* state = hist + 256;
  u64* cand  = (u64*)(ws + keyBytes + 2048);
  float* gauss = (float*)(ws + keyBytes + 2048 + (size_t)CAND_CAP * 8);

  float* out = (float*)d_out;

  k_init<<<1, 256, 0, stream>>>(hist, state);
  k_keys<<<1024, 256, 0, stream>>>(positions, cam, keys, hist, N);
  k_pick<<<1, 256, 0, stream>>>(hist, state, 24);
  k_hist<<<1024, 256, 0, stream>>>(keys, hist, state, 16, N);
  k_pick<<<1, 256, 0, stream>>>(hist, state, 16);
  k_hist<<<1024, 256, 0, stream>>>(keys, hist, state, 8, N);
  k_pick<<<1, 256, 0, stream>>>(hist, state, 8);
  k_hist<<<1024, 256, 0, stream>>>(keys, hist, state, 0, N);
  k_pick<<<1, 256, 0, stream>>>(hist, state, 0);
  k_collect<<<1024, 256, 0, stream>>>(keys, state, cand, N);
  k_sortprep<<<1, 1024, 0, stream>>>(state, cand, positions, scales, rotations,
                                     colors, opacity, colors_sh, cam, campos,
                                     gauss, shstride);
  k_render<<<256, 256, 0, stream>>>(gauss, out);
}

// Round 2
// 436.040 us; speedup vs baseline: 4.6889x; 4.6889x over previous
//
#include <hip/hip_runtime.h>
#include <stdint.h>

typedef uint32_t u32;
typedef uint64_t u64;

#define KREN 1000
#define WIMG 256
#define HIMG 256
#define CAND_CAP 2048
#define GSTRIDE 12

// ---------- monotonic float -> u32 key (larger key == larger float) ----------
__device__ __forceinline__ u32 fkey(float f) {
  u32 b = __float_as_uint(f);
  return (b & 0x80000000u) ? ~b : (b | 0x80000000u);
}

// ---------- init: zero hist + state, set K ----------
__global__ void k_init(u32* __restrict__ hist, u32* __restrict__ state) {
  int t = threadIdx.x;
  hist[t] = 0;
  if (t < 8) state[t] = (t == 1) ? (u32)KREN : 0u;
}

// ---------- compute depth keys + level-0 (bits 31:24) histogram ----------
__global__ void k_keys(const float* __restrict__ pos, const float* __restrict__ cam,
                       u32* __restrict__ keys, u32* __restrict__ hist, int N) {
  __shared__ u32 h[256];
  for (int i = threadIdx.x; i < 256; i += blockDim.x) h[i] = 0;
  __syncthreads();
  float c8 = cam[8], c9 = cam[9], c10 = cam[10], c11 = cam[11];
  int stride = gridDim.x * blockDim.x;
  for (int i = blockIdx.x * blockDim.x + threadIdx.x; i < N; i += stride) {
    float x = pos[3 * i], y = pos[3 * i + 1], z = pos[3 * i + 2];
    float d = c8 * x + c9 * y + c10 * z + c11;
    u32 mk = fkey(d);
    keys[i] = mk;
    atomicAdd(&h[mk >> 24], 1u);
  }
  __syncthreads();
  for (int i = threadIdx.x; i < 256; i += blockDim.x)
    if (h[i]) atomicAdd(&hist[i], h[i]);
}

// ---------- histogram of byte (shift..shift+7) among items matching prefix ----------
// LDS-privatized: global atomics only for the <=256-entry per-block flush.
__global__ void k_hist(const u32* __restrict__ keys, u32* __restrict__ hist,
                       const u32* __restrict__ state, int shift, int N) {
  __shared__ u32 h[256];
  for (int i = threadIdx.x; i < 256; i += blockDim.x) h[i] = 0;
  __syncthreads();
  u32 pref = state[0];
  u32 mask = ~((1u << (shift + 8)) - 1u);
  int stride = gridDim.x * blockDim.x;
  for (int i = blockIdx.x * blockDim.x + threadIdx.x; i < N; i += stride) {
    u32 k = keys[i];
    if ((k & mask) == pref) atomicAdd(&h[(k >> shift) & 255u], 1u);
  }
  __syncthreads();
  for (int i = threadIdx.x; i < 256; i += blockDim.x)
    if (h[i]) atomicAdd(&hist[i], h[i]);
}

// ---------- pick the bin holding the K-th largest; update prefix; clear hist ----------
__global__ void k_pick(u32* __restrict__ hist, u32* __restrict__ state, int shift) {
  __shared__ u32 h[256];
  int t = threadIdx.x;
  h[t] = hist[t];
  hist[t] = 0;  // ready for next level
  __syncthreads();
  if (t == 0) {
    u32 K = state[1];
    u32 cum = 0;
    int b = 255;
    for (; b >= 0; --b) {
      cum += h[b];
      if (cum >= K) break;
    }
    if (b < 0) b = 0;  // defensive; invariant guarantees break
    u32 above = cum - h[b];          // count strictly greater bins
    state[1] = K - above;            // remaining needed inside bin b
    state[0] |= ((u32)b) << shift;   // extend prefix
  }
}

// ---------- collect all candidates with key >= threshold ----------
__global__ void k_collect(const u32* __restrict__ keys, u32* __restrict__ state,
                          u64* __restrict__ cand, int N) {
  u32 T = state[0];
  int stride = gridDim.x * blockDim.x;
  for (int i = blockIdx.x * blockDim.x + threadIdx.x; i < N; i += stride) {
    u32 k = keys[i];
    if (k >= T) {
      u32 p = atomicAdd(&state[2], 1u);
      if (p < CAND_CAP) cand[p] = (((u64)(~k)) << 32) | (u32)i;
    }
  }
}

// ---------- single block: bitonic sort candidates, preprocess top-K gaussians ----------
__global__ __launch_bounds__(1024) void k_sortprep(
    const u32* __restrict__ state, const u64* __restrict__ cand,
    const float* __restrict__ pos, const float* __restrict__ scales,
    const float* __restrict__ rot, const float* __restrict__ colors,
    const float* __restrict__ opacity, const float* __restrict__ csh,
    const float* __restrict__ cam, const float* __restrict__ campos,
    float* __restrict__ gauss, int shstride) {
  __shared__ u64 s[CAND_CAP];
  int tid = threadIdx.x;
  int M = (int)state[2];
  if (M > CAND_CAP) M = CAND_CAP;
  for (int i = tid; i < CAND_CAP; i += 1024) s[i] = (i < M) ? cand[i] : ~0ull;
  __syncthreads();
  // bitonic ascending: key = (~depthkey, index) => depth desc, index asc (stable)
  for (int k = 2; k <= CAND_CAP; k <<= 1) {
    for (int j = k >> 1; j > 0; j >>= 1) {
      for (int t = tid; t < CAND_CAP; t += 1024) {
        int ixj = t ^ j;
        if (ixj > t) {
          u64 a = s[t], b = s[ixj];
          bool up = ((t & k) == 0);
          if (up ? (a > b) : (a < b)) { s[t] = b; s[ixj] = a; }
        }
      }
      __syncthreads();
    }
  }
  if (tid < KREN) {
    int g = (int)(u32)(s[tid] & 0xffffffffu);
    float x = pos[3 * g], y = pos[3 * g + 1], z = pos[3 * g + 2];
    float c0 = cam[0], c1 = cam[1], c2 = cam[2], c3 = cam[3];
    float c4 = cam[4], c5 = cam[5], c6 = cam[6], c7 = cam[7];
    float c8 = cam[8], c9 = cam[9], c10 = cam[10], c11 = cam[11];
    float dep = c8 * x + c9 * y + c10 * z + c11;
    float invd = 1.0f / (dep + 1e-7f);
    float p2x = (c0 * x + c1 * y + c2 * z + c3) * invd;
    float p2y = (c4 * x + c5 * y + c6 * z + c7) * invd;
    // normalized quaternion -> rotation matrix
    float qw = rot[4 * g], qx = rot[4 * g + 1], qy = rot[4 * g + 2], qz = rot[4 * g + 3];
    float qn = rsqrtf(qw * qw + qx * qx + qy * qy + qz * qz);
    qw *= qn; qx *= qn; qy *= qn; qz *= qn;
    float r00 = 1.f - 2.f * (qy * qy + qz * qz), r01 = 2.f * (qx * qy - qw * qz), r02 = 2.f * (qx * qz + qw * qy);
    float r10 = 2.f * (qx * qy + qw * qz), r11 = 1.f - 2.f * (qx * qx + qz * qz), r12 = 2.f * (qy * qz - qw * qx);
    float r20 = 2.f * (qx * qz - qw * qy), r21 = 2.f * (qy * qz + qw * qx), r22 = 1.f - 2.f * (qx * qx + qy * qy);
    float e0 = fmaxf(expf(scales[3 * g]), 1e-7f);
    float e1 = fmaxf(expf(scales[3 * g + 1]), 1e-7f);
    float e2 = fmaxf(expf(scales[3 * g + 2]), 1e-7f);
    float v0 = e0 * e0, v1 = e1 * e1, v2 = e2 * e2;
    float C00 = r00 * r00 * v0 + r01 * r01 * v1 + r02 * r02 * v2;
    float C01 = r00 * r10 * v0 + r01 * r11 * v1 + r02 * r12 * v2;
    float C02 = r00 * r20 * v0 + r01 * r21 * v1 + r02 * r22 * v2;
    float C11 = r10 * r10 * v0 + r11 * r11 * v1 + r12 * r12 * v2;
    float C12 = r10 * r20 * v0 + r11 * r21 * v1 + r12 * r22 * v2;
    float C22 = r20 * r20 * v0 + r21 * r21 * v1 + r22 * r22 * v2;
    float fx = c0, fy = c5;
    float jd = 1.0f / dep;  // reference J uses raw depth (no epsilon)
    float j0 = fx * jd, j2 = -fx * p2x * jd, j4 = fy * jd, j5 = -fy * p2y * jd;
    float u0x = j0 * C00 + j2 * C02;
    float u0y = j0 * C01 + j2 * C12;
    float u0z = j0 * C02 + j2 * C22;
    float u1y = j4 * C11 + j5 * C12;
    float u1z = j4 * C12 + j5 * C22;
    float a = u0x * j0 + u0z * j2 + 1e-6f;
    float b = u0y * j4 + u0z * j5;          // symmetric: b == cc
    float d2 = u1y * j4 + u1z * j5 + 1e-6f;
    float det = a * d2 - b * b;
    float idet = 1.0f / det;
    const float L = 1.4426950408889634f;    // log2(e)
    float Aq = -0.5f * L * d2 * idet;       // exp(-0.5*qv) == exp2(Aq dx^2 + Bq dxdy + Cq dy^2)
    float Bq = L * b * idet;
    float Cq = -0.5f * L * a * idet;
    // SH color
    float vx = x - campos[0], vy = y - campos[1], vz = z - campos[2];
    float vn = rsqrtf(vx * vx + vy * vy + vz * vz);
    vx *= vn; vy *= vn; vz *= vn;
    float sh[9];
    sh[0] = 0.28209479177387814f;
    sh[1] = -0.48860251190291987f * vy;
    sh[2] = 0.48860251190291987f * vz;
    sh[3] = -0.48860251190291987f * vx;
    sh[4] = 1.0925484305920792f * vx * vy;
    sh[5] = -1.0925484305920792f * vy * vz;
    sh[6] = 0.31539156525252005f * (2.f * vz * vz - vx * vx - vy * vy);
    sh[7] = -1.0925484305920792f * vx * vz;
    sh[8] = 0.5462742152960396f * (vx * vx - vy * vy);
    float col[3];
    for (int c = 0; c < 3; ++c) {
      float accv = colors[3 * g + c];
      for (int k2 = 0; k2 < 9; ++k2) accv += sh[k2] * csh[(size_t)g * shstride + 3 * k2 + c];
      col[c] = 1.0f / (1.0f + __expf(-accv));
    }
    float op = 1.0f / (1.0f + __expf(-opacity[g]));
    float* G = gauss + tid * GSTRIDE;
    G[0] = p2x; G[1] = p2y; G[2] = Aq; G[3] = Bq; G[4] = Cq;
    G[5] = op;  G[6] = col[0]; G[7] = col[1]; G[8] = col[2];
    G[9] = 0.f; G[10] = 0.f; G[11] = 0.f;
  }
}

// ---------- render: one thread per pixel, gaussians staged in LDS ----------
__global__ __launch_bounds__(256) void k_render(const float* __restrict__ gauss,
                                                float* __restrict__ out) {
  __shared__ float gs[KREN * GSTRIDE];  // 48 KB
  for (int i = threadIdx.x; i < KREN * GSTRIDE; i += 256) gs[i] = gauss[i];
  __syncthreads();
  int p = blockIdx.x * 256 + threadIdx.x;
  float px = (float)(p & (WIMG - 1));
  float py = (float)(p >> 8);
  float cr = 0.f, cg = 0.f, cb = 0.f, acc = 0.f;
  for (int k = 0; k < KREN; ++k) {
    const float4* G = (const float4*)(gs + k * GSTRIDE);
    float4 g0 = G[0];
    float4 g1 = G[1];
    float g2x = gs[k * GSTRIDE + 8];
    float dx = px - g0.x, dy = py - g0.y;
    float sE = g0.z * dx * dx + g0.w * dx * dy + g1.x * dy * dy;
    float alpha = g1.y * exp2f(sE);
    float w = (1.0f - acc) * alpha;
    cr += w * g1.z; cg += w * g1.w; cb += w * g2x;
    acc += w;
  }
  out[3 * p + 0] = cr;
  out[3 * p + 1] = cg;
  out[3 * p + 2] = cb;
}

extern "C" void kernel_launch(void* const* d_in, const int* in_sizes, int n_in,
                              void* d_out, int out_size, void* d_ws, size_t ws_size,
                              hipStream_t stream) {
  const float* positions = (const float*)d_in[0];
  const float* scales    = (const float*)d_in[1];
  const float* rotations = (const float*)d_in[2];
  const float* colors    = (const float*)d_in[3];
  const float* opacity   = (const float*)d_in[4];
  const float* colors_sh = (const float*)d_in[5];
  const float* cam       = (const float*)d_in[6];
  const float* campos    = (const float*)d_in[7];
  int N = in_sizes[0] / 3;
  int shstride = in_sizes[5] / N;  // = SH_COEFFS * 3 = 48

  char* ws = (char*)d_ws;
  size_t keyBytes = (((size_t)N * 4) + 255) & ~(size_t)255;
  u32* keys  = (u32*)ws;
  u32* hist  = (u32*)(ws + keyBytes);
  u32* state = hist + 256;
  u64* cand  = (u64*)(ws + keyBytes + 2048);
  float* gauss = (float*)(ws + keyBytes + 2048 + (size_t)CAND_CAP * 8);

  float* out = (float*)d_out;

  k_init<<<1, 256, 0, stream>>>(hist, state);
  k_keys<<<1024, 256, 0, stream>>>(positions, cam, keys, hist, N);
  k_pick<<<1, 256, 0, stream>>>(hist, state, 24);
  k_hist<<<1024, 256, 0, stream>>>(keys, hist, state, 16, N);
  k_pick<<<1, 256, 0, stream>>>(hist, state, 16);
  k_hist<<<1024, 256, 0, stream>>>(keys, hist, state, 8, N);
  k_pick<<<1, 256, 0, stream>>>(hist, state, 8);
  k_hist<<<1024, 256, 0, stream>>>(keys, hist, state, 0, N);
  k_pick<<<1, 256, 0, stream>>>(hist, state, 0);
  k_collect<<<1024, 256, 0, stream>>>(keys, state, cand, N);
  k_sortprep<<<1, 1024, 0, stream>>>(state, cand, positions, scales, rotations,
                                     colors, opacity, colors_sh, cam, campos,
                                     gauss, shstride);
  k_render<<<256, 256, 0, stream>>>(gauss, out);
}